// Round 1
// baseline (585.382 us; speedup 1.0000x reference)
//
#include <hip/hip_runtime.h>
#include <hip/hip_bf16.h>

#define VOCAB 32000
#define NUM_CLASS 16
#define HID 256
#define BATCH 2048

typedef __attribute__((ext_vector_type(8))) __bf16 bf16x8;
typedef __attribute__((ext_vector_type(4))) float floatx4;

// RNE f32 -> bf16 (finite inputs)
__device__ __forceinline__ unsigned short f32_to_bf16_u16(float f) {
    union { float f; unsigned u; } a;
    a.f = f;
    unsigned r = a.u + 0x7fffu + ((a.u >> 16) & 1u);
    return (unsigned short)(r >> 16);
}

// ---------------------------------------------------------------------------
// Stage 1: h_t[c][k] = tanh( W[z[c]][k] . E[x[c]] + U[z[c]][k] . h[c] )
// One block per batch element c; thread t computes output k = t.
// Exact f32 math (h_t is output 1 and must be tight).
// ---------------------------------------------------------------------------
__global__ __launch_bounds__(256) void rnn_step_kernel(
    const int* __restrict__ x, const int* __restrict__ z,
    const float* __restrict__ h, const float* __restrict__ E,
    const float* __restrict__ W, const float* __restrict__ U,
    float* __restrict__ ht_f32,
    unsigned short* __restrict__ ht_bf16)
{
    __shared__ float s_e[HID];
    __shared__ float s_h[HID];
    const int c = blockIdx.x;
    const int t = threadIdx.x;
    const int xi = x[c];
    const int g  = z[c];          // NSTEP == 1, so z[0][c] == z[c]
    s_e[t] = E[(size_t)xi * HID + t];
    s_h[t] = h[(size_t)c * HID + t];
    __syncthreads();

    const float4* Wr = (const float4*)(W + (size_t)g * HID * HID + (size_t)t * HID);
    const float4* Ur = (const float4*)(U + (size_t)g * HID * HID + (size_t)t * HID);
    const float4* e4 = (const float4*)s_e;
    const float4* h4 = (const float4*)s_h;

    float4 acc = make_float4(0.f, 0.f, 0.f, 0.f);
#pragma unroll 8
    for (int i = 0; i < HID / 4; ++i) {
        float4 w = Wr[i], u = Ur[i], e = e4[i], hh = h4[i];
        acc.x += w.x * e.x + u.x * hh.x;
        acc.y += w.y * e.y + u.y * hh.y;
        acc.z += w.z * e.z + u.z * hh.z;
        acc.w += w.w * e.w + u.w * hh.w;
    }
    const float v = tanhf((acc.x + acc.y) + (acc.z + acc.w));
    ht_f32 [(size_t)c * HID + t] = v;
    ht_bf16[(size_t)c * HID + t] = f32_to_bf16_u16(v);
}

// ---------------------------------------------------------------------------
// Convert Vw (f32, VOCAB x HID) -> bf16 in workspace.
// ---------------------------------------------------------------------------
struct bf4 { unsigned short s[4]; };

__global__ __launch_bounds__(256) void cvt_vw_kernel(
    const float* __restrict__ src, unsigned short* __restrict__ dst, int n4)
{
    int i = blockIdx.x * blockDim.x + threadIdx.x;
    const int stride = gridDim.x * blockDim.x;
    for (; i < n4; i += stride) {
        float4 v = ((const float4*)src)[i];
        bf4 o;
        o.s[0] = f32_to_bf16_u16(v.x);
        o.s[1] = f32_to_bf16_u16(v.y);
        o.s[2] = f32_to_bf16_u16(v.z);
        o.s[3] = f32_to_bf16_u16(v.w);
        ((bf4*)dst)[i] = o;
    }
}

// ---------------------------------------------------------------------------
// Stage 2: logits[c][v] = sum_k ht[c][k] * Vw[v][k] + Vb[v]
// M=2048, N=32000, K=256; A (M x K) and B^T (N x K) both K-contiguous bf16.
// Block = 4 waves, 128x128 tile; wave = 64x64 (4x4 MFMA 16x16x32 tiles).
// Fragments loaded directly from global (L2-resident; no LDS this round).
// MFMA layouts (HW-verified m89/m120):
//   A frag: A[m = lane&15][k = (lane>>4)*8 + j], j in [0,8)
//   B frag: B^T[n = lane&15][k = (lane>>4)*8 + j]
//   D:      row = (lane>>4)*4 + r, col = lane&15
// ---------------------------------------------------------------------------
__global__ __launch_bounds__(256) void out_gemm_kernel(
    const unsigned short* __restrict__ A,   // ht bf16, 2048 x 256
    const unsigned short* __restrict__ B,   // Vw bf16, 32000 x 256
    const float* __restrict__ Vb,
    float* __restrict__ C)                  // 2048 x 32000
{
    const int lane = threadIdx.x & 63;
    const int wave = threadIdx.x >> 6;
    const int wr = wave >> 1, wc = wave & 1;
    const int m_wave = blockIdx.y * 128 + wr * 64;
    const int n_wave = blockIdx.x * 128 + wc * 64;
    const int lrow = lane & 15;
    const int quad = lane >> 4;
    const int kq   = quad * 8;

    floatx4 acc[4][4] = {};

#pragma unroll
    for (int k0 = 0; k0 < HID; k0 += 32) {
        bf16x8 a[4], b[4];
#pragma unroll
        for (int mi = 0; mi < 4; ++mi)
            a[mi] = *(const bf16x8*)(A + (size_t)(m_wave + mi * 16 + lrow) * HID + k0 + kq);
#pragma unroll
        for (int ni = 0; ni < 4; ++ni)
            b[ni] = *(const bf16x8*)(B + (size_t)(n_wave + ni * 16 + lrow) * HID + k0 + kq);
#pragma unroll
        for (int mi = 0; mi < 4; ++mi)
#pragma unroll
            for (int ni = 0; ni < 4; ++ni)
                acc[mi][ni] = __builtin_amdgcn_mfma_f32_16x16x32_bf16(
                    a[mi], b[ni], acc[mi][ni], 0, 0, 0);
    }

    const int row_q = quad * 4;
#pragma unroll
    for (int ni = 0; ni < 4; ++ni) {
        const int col = n_wave + ni * 16 + lrow;
        const float vb = Vb[col];
#pragma unroll
        for (int mi = 0; mi < 4; ++mi) {
            const int row = m_wave + mi * 16 + row_q;
            float* cp = C + (size_t)row * VOCAB + col;
#pragma unroll
            for (int r = 0; r < 4; ++r)
                cp[(size_t)r * VOCAB] = acc[mi][ni][r] + vb;
        }
    }
}

extern "C" void kernel_launch(void* const* d_in, const int* in_sizes, int n_in,
                              void* d_out, int out_size, void* d_ws, size_t ws_size,
                              hipStream_t stream) {
    const int*   x  = (const int*)d_in[0];
    const int*   z  = (const int*)d_in[1];
    const float* h  = (const float*)d_in[2];
    const float* E  = (const float*)d_in[3];
    const float* Vw = (const float*)d_in[4];
    const float* Vb = (const float*)d_in[5];
    const float* W  = (const float*)d_in[6];
    const float* U  = (const float*)d_in[7];

    float* logits = (float*)d_out;
    float* ht_out = logits + (size_t)BATCH * VOCAB;

    // workspace: [Vw_bf16: VOCAB*HID u16][ht_bf16: BATCH*HID u16]
    unsigned short* Vw_bf = (unsigned short*)d_ws;
    unsigned short* ht_bf = (unsigned short*)((char*)d_ws + (size_t)VOCAB * HID * 2);

    cvt_vw_kernel<<<2048, 256, 0, stream>>>(Vw, Vw_bf, VOCAB * HID / 4);
    rnn_step_kernel<<<BATCH, 256, 0, stream>>>(x, z, h, E, W, U, ht_out, ht_bf);
    out_gemm_kernel<<<dim3(VOCAB / 128, BATCH / 128), 256, 0, stream>>>(ht_bf, Vw_bf, Vb, logits);
}

// Round 2
// 479.236 us; speedup vs baseline: 1.2215x; 1.2215x over previous
//
#include <hip/hip_runtime.h>
#include <hip/hip_bf16.h>

#define VOCAB 32000
#define NUM_CLASS 16
#define HID 256
#define KCAT 512          // concat(e, h) K dimension
#define BATCH 2048

typedef __attribute__((ext_vector_type(8))) __bf16 bf16x8;
typedef __attribute__((ext_vector_type(4))) float floatx4;

// RNE f32 -> bf16 (finite inputs)
__device__ __forceinline__ unsigned short f32_to_bf16_u16(float f) {
    union { float f; unsigned u; } a;
    a.f = f;
    unsigned r = a.u + 0x7fffu + ((a.u >> 16) & 1u);
    return (unsigned short)(r >> 16);
}

struct bf8v { unsigned short s[8]; };

// ---------------------------------------------------------------------------
// Bucket batch elements by class: perm[bases[g] .. bases[g]+counts[g]) = c's
// with z[c]==g. Single block; order within a class is irrelevant.
// ---------------------------------------------------------------------------
__global__ __launch_bounds__(256) void bucket_kernel(
    const int* __restrict__ z, int* __restrict__ perm,
    int* __restrict__ counts, int* __restrict__ bases)
{
    __shared__ int s_cnt[NUM_CLASS];
    __shared__ int s_off[NUM_CLASS];
    const int t = threadIdx.x;
    if (t < NUM_CLASS) s_cnt[t] = 0;
    __syncthreads();
    for (int c = t; c < BATCH; c += 256) atomicAdd(&s_cnt[z[c]], 1);
    __syncthreads();
    if (t == 0) {
        int acc = 0;
        for (int i = 0; i < NUM_CLASS; ++i) { s_off[i] = acc; acc += s_cnt[i]; }
    }
    __syncthreads();
    if (t < NUM_CLASS) { counts[t] = s_cnt[t]; bases[t] = s_off[t]; }
    __syncthreads();
    for (int c = t; c < BATCH; c += 256) {
        int p = atomicAdd(&s_off[z[c]], 1);
        perm[p] = c;
    }
}

// ---------------------------------------------------------------------------
// Build G (BATCH x KCAT bf16): G[c] = [bf16(E[x[c]]), bf16(h[c])]
// 8 elements per thread, coalesced along rows.
// ---------------------------------------------------------------------------
__global__ __launch_bounds__(256) void gather_g_kernel(
    const int* __restrict__ x, const float* __restrict__ E,
    const float* __restrict__ h, unsigned short* __restrict__ G)
{
    const int tid = blockIdx.x * 256 + threadIdx.x;   // BATCH*KCAT/8 threads
    const int c  = tid >> 6;          // 64 chunks of 8 per row
    const int j0 = (tid & 63) * 8;
    const float* src = (j0 < HID)
        ? (E + (size_t)x[c] * HID + j0)
        : (h + (size_t)c * HID + (j0 - HID));
    float4 v0 = ((const float4*)src)[0];
    float4 v1 = ((const float4*)src)[1];
    bf8v o;
    o.s[0] = f32_to_bf16_u16(v0.x); o.s[1] = f32_to_bf16_u16(v0.y);
    o.s[2] = f32_to_bf16_u16(v0.z); o.s[3] = f32_to_bf16_u16(v0.w);
    o.s[4] = f32_to_bf16_u16(v1.x); o.s[5] = f32_to_bf16_u16(v1.y);
    o.s[6] = f32_to_bf16_u16(v1.z); o.s[7] = f32_to_bf16_u16(v1.w);
    *(bf8v*)(G + (size_t)c * KCAT + j0) = o;
}

// ---------------------------------------------------------------------------
// Build Bcat (NUM_CLASS x HID x KCAT bf16): Bcat[g][k] = [W[g][k][:], U[g][k][:]]
// ---------------------------------------------------------------------------
__global__ __launch_bounds__(256) void cast_wu_kernel(
    const float* __restrict__ W, const float* __restrict__ U,
    unsigned short* __restrict__ Bcat)
{
    const int tid = blockIdx.x * 256 + threadIdx.x;   // NUM_CLASS*HID*KCAT/8
    const int row = tid >> 6;          // g*HID + k
    const int j0  = (tid & 63) * 8;
    const float* src = (j0 < HID)
        ? (W + (size_t)row * HID + j0)
        : (U + (size_t)row * HID + (j0 - HID));
    float4 v0 = ((const float4*)src)[0];
    float4 v1 = ((const float4*)src)[1];
    bf8v o;
    o.s[0] = f32_to_bf16_u16(v0.x); o.s[1] = f32_to_bf16_u16(v0.y);
    o.s[2] = f32_to_bf16_u16(v0.z); o.s[3] = f32_to_bf16_u16(v0.w);
    o.s[4] = f32_to_bf16_u16(v1.x); o.s[5] = f32_to_bf16_u16(v1.y);
    o.s[6] = f32_to_bf16_u16(v1.z); o.s[7] = f32_to_bf16_u16(v1.w);
    *(bf8v*)(Bcat + (size_t)row * KCAT + j0) = o;
}

// ---------------------------------------------------------------------------
// Convert Vw (f32, VOCAB x HID) -> bf16 in workspace.
// ---------------------------------------------------------------------------
struct bf4 { unsigned short s[4]; };

__global__ __launch_bounds__(256) void cvt_vw_kernel(
    const float* __restrict__ src, unsigned short* __restrict__ dst, int n4)
{
    int i = blockIdx.x * blockDim.x + threadIdx.x;
    const int stride = gridDim.x * blockDim.x;
    for (; i < n4; i += stride) {
        float4 v = ((const float4*)src)[i];
        bf4 o;
        o.s[0] = f32_to_bf16_u16(v.x);
        o.s[1] = f32_to_bf16_u16(v.y);
        o.s[2] = f32_to_bf16_u16(v.z);
        o.s[3] = f32_to_bf16_u16(v.w);
        ((bf4*)dst)[i] = o;
    }
}

// ---------------------------------------------------------------------------
// Stage 1 as per-class GEMM: for class g, rows c in bucket:
//   ht[c][k] = tanh( G[c][:] . Bcat[g][k][:] )   (K = 512)
// Grid: (m_tile, class). Block 256 thr = 4 waves; tile M=32, N=256 (HID).
// Wave w: n in [w*64, w*64+64), 2 m-tiles x 4 n-tiles of 16x16x32 MFMA.
// A rows gathered via perm (uncoalesced 16B lane loads, but tiny & L2-hot).
// ---------------------------------------------------------------------------
__global__ __launch_bounds__(256) void rnn_gemm_kernel(
    const unsigned short* __restrict__ G,     // BATCH x KCAT
    const unsigned short* __restrict__ Bcat,  // NUM_CLASS x HID x KCAT
    const int* __restrict__ perm, const int* __restrict__ counts,
    const int* __restrict__ bases,
    float* __restrict__ ht_f32, unsigned short* __restrict__ ht_bf16)
{
    const int g = blockIdx.y;
    const int cnt = counts[g];
    const int mstart = blockIdx.x * 32;
    if (mstart >= cnt) return;
    const int base = bases[g];

    __shared__ int s_rows[32];
    if (threadIdx.x < 32) {
        int mi = mstart + threadIdx.x;
        s_rows[threadIdx.x] = perm[base + (mi < cnt ? mi : cnt - 1)];
    }
    __syncthreads();

    const int lane = threadIdx.x & 63;
    const int wave = threadIdx.x >> 6;
    const int n0   = wave * 64;
    const int lrow = lane & 15;
    const int quad = lane >> 4;
    const int kq   = quad * 8;

    const unsigned short* Bg = Bcat + (size_t)g * HID * KCAT;

    floatx4 acc[2][4] = {};
#pragma unroll 4
    for (int k0 = 0; k0 < KCAT; k0 += 32) {
        bf16x8 a[2], b[4];
#pragma unroll
        for (int mi = 0; mi < 2; ++mi) {
            const int row = s_rows[mi * 16 + lrow];
            a[mi] = *(const bf16x8*)(G + (size_t)row * KCAT + k0 + kq);
        }
#pragma unroll
        for (int ni = 0; ni < 4; ++ni)
            b[ni] = *(const bf16x8*)(Bg + (size_t)(n0 + ni * 16 + lrow) * KCAT + k0 + kq);
#pragma unroll
        for (int mi = 0; mi < 2; ++mi)
#pragma unroll
            for (int ni = 0; ni < 4; ++ni)
                acc[mi][ni] = __builtin_amdgcn_mfma_f32_16x16x32_bf16(
                    a[mi], b[ni], acc[mi][ni], 0, 0, 0);
    }

#pragma unroll
    for (int mi = 0; mi < 2; ++mi) {
#pragma unroll
        for (int r = 0; r < 4; ++r) {
            const int midx = mi * 16 + quad * 4 + r;
            if (mstart + midx >= cnt) continue;
            const int c = s_rows[midx];
#pragma unroll
            for (int ni = 0; ni < 4; ++ni) {
                const int k = n0 + ni * 16 + lrow;
                const float v = tanhf(acc[mi][ni][r]);
                ht_f32 [(size_t)c * HID + k] = v;
                ht_bf16[(size_t)c * HID + k] = f32_to_bf16_u16(v);
            }
        }
    }
}

// ---------------------------------------------------------------------------
// Stage 2: logits = ht . Vw^T + Vb   (M=2048, N=32000, K=256) — unchanged.
// ---------------------------------------------------------------------------
__global__ __launch_bounds__(256) void out_gemm_kernel(
    const unsigned short* __restrict__ A,   // ht bf16, 2048 x 256
    const unsigned short* __restrict__ B,   // Vw bf16, 32000 x 256
    const float* __restrict__ Vb,
    float* __restrict__ C)                  // 2048 x 32000
{
    const int lane = threadIdx.x & 63;
    const int wave = threadIdx.x >> 6;
    const int wr = wave >> 1, wc = wave & 1;
    const int m_wave = blockIdx.y * 128 + wr * 64;
    const int n_wave = blockIdx.x * 128 + wc * 64;
    const int lrow = lane & 15;
    const int quad = lane >> 4;
    const int kq   = quad * 8;

    floatx4 acc[4][4] = {};

#pragma unroll
    for (int k0 = 0; k0 < HID; k0 += 32) {
        bf16x8 a[4], b[4];
#pragma unroll
        for (int mi = 0; mi < 4; ++mi)
            a[mi] = *(const bf16x8*)(A + (size_t)(m_wave + mi * 16 + lrow) * HID + k0 + kq);
#pragma unroll
        for (int ni = 0; ni < 4; ++ni)
            b[ni] = *(const bf16x8*)(B + (size_t)(n_wave + ni * 16 + lrow) * HID + k0 + kq);
#pragma unroll
        for (int mi = 0; mi < 4; ++mi)
#pragma unroll
            for (int ni = 0; ni < 4; ++ni)
                acc[mi][ni] = __builtin_amdgcn_mfma_f32_16x16x32_bf16(
                    a[mi], b[ni], acc[mi][ni], 0, 0, 0);
    }

    const int row_q = quad * 4;
#pragma unroll
    for (int ni = 0; ni < 4; ++ni) {
        const int col = n_wave + ni * 16 + lrow;
        const float vb = Vb[col];
#pragma unroll
        for (int mi = 0; mi < 4; ++mi) {
            const int row = m_wave + mi * 16 + row_q;
            float* cp = C + (size_t)row * VOCAB + col;
#pragma unroll
            for (int r = 0; r < 4; ++r)
                cp[(size_t)r * VOCAB] = acc[mi][ni][r] + vb;
        }
    }
}

extern "C" void kernel_launch(void* const* d_in, const int* in_sizes, int n_in,
                              void* d_out, int out_size, void* d_ws, size_t ws_size,
                              hipStream_t stream) {
    const int*   x  = (const int*)d_in[0];
    const int*   z  = (const int*)d_in[1];
    const float* h  = (const float*)d_in[2];
    const float* E  = (const float*)d_in[3];
    const float* Vw = (const float*)d_in[4];
    const float* Vb = (const float*)d_in[5];
    const float* W  = (const float*)d_in[6];
    const float* U  = (const float*)d_in[7];

    float* logits = (float*)d_out;
    float* ht_out = logits + (size_t)BATCH * VOCAB;

    // workspace layout
    char* p = (char*)d_ws;
    unsigned short* Vw_bf = (unsigned short*)p;  p += (size_t)VOCAB * HID * 2;
    unsigned short* ht_bf = (unsigned short*)p;  p += (size_t)BATCH * HID * 2;
    unsigned short* G     = (unsigned short*)p;  p += (size_t)BATCH * KCAT * 2;
    unsigned short* Bcat  = (unsigned short*)p;  p += (size_t)NUM_CLASS * HID * KCAT * 2;
    int* perm   = (int*)p;  p += BATCH * 4;
    int* counts = (int*)p;  p += NUM_CLASS * 4;
    int* bases  = (int*)p;  p += NUM_CLASS * 4;

    bucket_kernel<<<1, 256, 0, stream>>>(z, perm, counts, bases);
    gather_g_kernel<<<BATCH * KCAT / 8 / 256, 256, 0, stream>>>(x, E, h, G);
    cast_wu_kernel<<<NUM_CLASS * HID * KCAT / 8 / 256, 256, 0, stream>>>(W, U, Bcat);
    cvt_vw_kernel<<<2048, 256, 0, stream>>>(Vw, Vw_bf, VOCAB * HID / 4);
    rnn_gemm_kernel<<<dim3(BATCH / 32, NUM_CLASS), 256, 0, stream>>>(
        G, Bcat, perm, counts, bases, ht_out, ht_bf);
    out_gemm_kernel<<<dim3(VOCAB / 128, BATCH / 128), 256, 0, stream>>>(ht_bf, Vw_bf, Vb, logits);
}